// Round 5
// baseline (14279.362 us; speedup 1.0000x reference)
//
#include <hip/hip_runtime.h>
#include <math.h>

// ---------------------------------------------------------------------------
// Generator_429496729630 — round 7: k_heads occupancy (LDS overlay).
//
// r6 post-mortem: phase split landed (13.7ms). Top-5 = k_heads x5 @ 3.9ms --
// now the largest single kernel. Counters: VALUBusy 19%, Occupancy 29%
// (= 3 blocks/CU, LDS-capped at 43KB), L2 traffic 14.3GB @ only 3.7TB/s ->
// latency-bound, not BW-bound. Floor is 370us (58 GFLOP @ 157TF fp32).
//
// Fix: sN (now_emb staging) is dead after the attr MLPs -> overlay sH onto
// the same 16KB buffer (stage now_emb -> attr -> barrier -> reload buffer
// with hidden -> main GEMM). LDS 43 -> 26.6KB -> 6 blocks/CU = 24 waves/CU;
// __launch_bounds__(256,6). FP accumulation order identical. No other kernel
// touched.
// ---------------------------------------------------------------------------

#define B_    256
#define T_    64
#define EMB_  128
#define HID_  512
#define G4_   2048
#define CIN_  704
#define HA_   576
#define ROW_  3072
#define OFF_HA 2048
#define OFF_HB 2560

// phase-B LDS geometry (float indices)
#define WKB_   516            // kb-subblock stride: 8*64 + 4 pad (bank spread)
#define WKC_   4128           // kc-block stride: 8*WKB_
#define HB0_   33024          // = 8*WKC_ ; hbuf / reduction-slab region (2 x 2048)
#define SMEM_F 37120          // 145 KiB

// barrier word layout in ws: team tau: cnt @ 64 + tau*32, gen @ +16
#define BAR_T(tau) (64 + (tau) * 32)

struct Params {
  const float* label; const int* length; const int* x; const int* xnow;
  const float* emb[5]; const float* pad;
  const float* condW[4]; const float* condB[4];
  const float* lenW; const float* lenB;
  const float* combW; const float* combB;
  const float* Wih; const float* Whh; const float* bih; const float* bhh;
  const float* outW[5]; const float* outB[5];
  unsigned int* bar;
  float* out;
};

// generation-based multi-block barrier (agent scope).
// RELAXED spin + single ACQUIRE load at exit; ordering via fetch_add(ACQ_REL)
// + store(RELEASE). (r5: one 64B line per variable, no per-poll cache inv.)
__device__ __forceinline__ void multi_barrier(unsigned int* cnt, unsigned int* gen,
                                              unsigned int n) {
  __syncthreads();
  if (threadIdx.x == 0) {
    unsigned int g = __hip_atomic_load(gen, __ATOMIC_RELAXED, __HIP_MEMORY_SCOPE_AGENT);
    unsigned int a = __hip_atomic_fetch_add(cnt, 1u, __ATOMIC_ACQ_REL, __HIP_MEMORY_SCOPE_AGENT);
    if (a == n - 1u) {
      __hip_atomic_store(cnt, 0u, __ATOMIC_RELAXED, __HIP_MEMORY_SCOPE_AGENT);
      __hip_atomic_store(gen, g + 1u, __ATOMIC_RELEASE, __HIP_MEMORY_SCOPE_AGENT);
    } else {
      while (__hip_atomic_load(gen, __ATOMIC_RELAXED, __HIP_MEMORY_SCOPE_AGENT) == g) {
        __builtin_amdgcn_s_sleep(2);
      }
      (void)__hip_atomic_load(gen, __ATOMIC_ACQUIRE, __HIP_MEMORY_SCOPE_AGENT);
    }
  }
  __syncthreads();
}

// reduction-slab helpers: lane lo writes/reads its acc[8][8] as 16 float4,
// column-rotated by lane for bank spread.
#define WRSLAB(SL) do { \
  _Pragma("unroll") \
  for (int qq = 0; qq < 16; ++qq) { \
    int cc = ((qq + lo) & 15) * 4; \
    *(float4*)&(SL)[lo * 64 + cc] = \
      make_float4(acc[qq >> 1][(qq & 1) * 4 + 0], acc[qq >> 1][(qq & 1) * 4 + 1], \
                  acc[qq >> 1][(qq & 1) * 4 + 2], acc[qq >> 1][(qq & 1) * 4 + 3]); \
  } } while (0)

#define RDSLAB(SL) do { \
  _Pragma("unroll") \
  for (int qq = 0; qq < 16; ++qq) { \
    int cc = ((qq + lo) & 15) * 4; \
    float4 vv = *(const float4*)&(SL)[lo * 64 + cc]; \
    acc[qq >> 1][(qq & 1) * 4 + 0] += vv.x; acc[qq >> 1][(qq & 1) * 4 + 1] += vv.y; \
    acc[qq >> 1][(qq & 1) * 4 + 2] += vv.z; acc[qq >> 1][(qq & 1) * 4 + 3] += vv.w; \
  } } while (0)

// ---------------- T1: transpose Wih -> Wt_ih into OUT slot ----------------
__global__ __launch_bounds__(256) void k_t1(Params P, int l) {
  __shared__ float sm[4608];
  const int out_off = (l & 1) ? OFF_HA : OFF_HB;
  const float* Wih = P.Wih + (size_t)l * G4_ * HID_;
  const int tid = threadIdx.x, blk = blockIdx.x;
  const int rt = blk >> 4, kt = blk & 15;
  const int r0 = rt * 128, k0 = kt * 32;
  const int ul = tid >> 3, kl = (tid & 7) * 4;
  #pragma unroll
  for (int p = 0; p < 4; ++p) {
    float4 v = *(const float4*)(Wih + (size_t)(r0 + p * 32 + ul) * HID_ + k0 + kl);
    *(float4*)&sm[(p * 32 + ul) * 36 + kl] = v;
  }
  __syncthreads();
  const int kk = tid >> 3, qb = (tid & 7) * 4;
  #pragma unroll
  for (int p = 0; p < 4; ++p) {
    int rl = qb + p * 32;
    float4 v = make_float4(sm[(rl + 0) * 36 + kk], sm[(rl + 1) * 36 + kk],
                           sm[(rl + 2) * 36 + kk], sm[(rl + 3) * 36 + kk]);
    int kabs = k0 + kk;
    int row = (r0 >> 8) * 256 + (kabs >> 1);
    int col = out_off + (kabs & 1) * 256 + (r0 & 255) + rl;
    *(float4*)&P.out[(size_t)row * ROW_ + col] = v;
  }
}

// ---------------- A: G = h_in @ Wih^T + bih + bhh ----------------
// 1024 blocks: rb = bid>>1 picks 32 rows, ch = bid&1 picks 1024 cols.
// 3 waves/SIMD (launch_bounds) to hide load latency.
__global__ __launch_bounds__(256, 3) void k_gih(Params P, int l) {
  const int in_off  = (l & 1) ? OFF_HB : OFF_HA;
  const int out_off = (l & 1) ? OFF_HA : OFF_HB;
  const int tid = threadIdx.x;
  const int rg = tid & 63, mh = tid >> 6;
  const int rb = blockIdx.x >> 1, ch = blockIdx.x & 1;
  const int m_base = rb * 32;
  const float* arow[8];
  #pragma unroll
  for (int mm = 0; mm < 8; ++mm)
    arow[mm] = P.out + (size_t)(m_base + mh * 8 + mm) * ROW_ + in_off;
  for (int p0 = 0; p0 < 4; ++p0) {
    const int p = ch * 4 + p0;
    float acc[4][8];
    #pragma unroll
    for (int c = 0; c < 4; ++c)
      #pragma unroll
      for (int m = 0; m < 8; ++m) acc[c][m] = 0.f;
    const float* wp = P.out + (size_t)(p * 256) * ROW_ + out_off + rg * 4;
    for (int kq = 0; kq < 64; ++kq) {
      float4 w0 = *(const float4*)(wp);              // k=4kq
      float4 w1 = *(const float4*)(wp + 256);        // k=4kq+1
      float4 w2 = *(const float4*)(wp + ROW_);       // k=4kq+2
      float4 w3 = *(const float4*)(wp + ROW_ + 256); // k=4kq+3
      #pragma unroll
      for (int mm = 0; mm < 8; ++mm) {
        float4 a = *(const float4*)(arow[mm] + kq * 4);
        acc[0][mm] += w0.x * a.x + w1.x * a.y + w2.x * a.z + w3.x * a.w;
        acc[1][mm] += w0.y * a.x + w1.y * a.y + w2.y * a.z + w3.y * a.w;
        acc[2][mm] += w0.z * a.x + w1.z * a.y + w2.z * a.z + w3.z * a.w;
        acc[3][mm] += w0.w * a.x + w1.w * a.y + w2.w * a.z + w3.w * a.w;
      }
      wp += 2 * ROW_;
    }
    int r4 = p * 256 + rg * 4;
    float4 bi = *(const float4*)(P.bih + l * G4_ + r4);
    float4 bh = *(const float4*)(P.bhh + l * G4_ + r4);
    float bx = bi.x + bh.x, by = bi.y + bh.y, bz = bi.z + bh.z, bw = bi.w + bh.w;
    #pragma unroll
    for (int mm = 0; mm < 8; ++mm) {
      int m = m_base + mh * 8 + mm;
      *(float4*)&P.out[(size_t)m * ROW_ + r4] =
        make_float4(acc[0][mm] + bx, acc[1][mm] + by,
                    acc[2][mm] + bz, acc[3][mm] + bw);
    }
  }
}

// ---------------- B: recurrent steps, Whh slice resident in LDS ----------
__global__ __launch_bounds__(256, 1) void k_lstmB(Params P, int l) {
  __shared__ float smem[SMEM_F];
  unsigned int* bar = P.bar;
  const int tid = threadIdx.x;
  const int blk = blockIdx.x;
  const int team = blk & 7, member = blk >> 3;   // 8 teams x 32 members
  const int out_off = (l & 1) ? OFF_HA : OFF_HB;

  const int kb  = tid >> 5;          // 0..7 k-slice
  const int sgq = (tid >> 3) & 3;    // 0..3 sample group (8 samples)
  const int rg  = tid & 7;           // 0..7 row group
  const bool owner = (tid < 32);
  const int s_base = team * 32 + sgq * 8;
  const int ucol0  = member * 16 + rg * 2;

  // load this member's Whh slice: local row r = i*4+g  (i=unit&15, g=gate)
  // LDS addr(k,r) = (k>>6)*WKC_ + ((k>>3)&7)*WKB_ + (k&7)*64 + r
  {
    const float* Wl = P.Whh + (size_t)l * G4_ * HID_;
    const int r = tid >> 2, q = tid & 3;
    const float* src = Wl + (size_t)((r & 3) * 512 + member * 16 + (r >> 2)) * HID_
                       + q * 128;
    for (int j = 0; j < 32; ++j) {
      float4 v = *(const float4*)(src + j * 4);
      int k0 = q * 128 + j * 4;
      #pragma unroll
      for (int e = 0; e < 4; ++e) {
        int k = k0 + e;
        smem[(k >> 6) * WKC_ + ((k >> 3) & 7) * WKB_ + (k & 7) * 64 + r] = (&v.x)[e];
      }
    }
  }
  __syncthreads();

  float cst[8][2];   // owner c-state: 8 samples x 2 units

  // ---- t = 0: h_prev = 0, gates = G directly ----
  if (owner) {
    #pragma unroll
    for (int sj = 0; sj < 8; ++sj) {
      const size_t grow = (size_t)((s_base + sj) * 64 + 0) * ROW_;
      float2 zi2 = *(const float2*)&P.out[grow + 0 * 512 + ucol0];
      float2 zg2 = *(const float2*)&P.out[grow + 2 * 512 + ucol0];
      float2 zo2 = *(const float2*)&P.out[grow + 3 * 512 + ucol0];
      #pragma unroll
      for (int uj = 0; uj < 2; ++uj) {
        float zi = (&zi2.x)[uj], zg = (&zg2.x)[uj], zo = (&zo2.x)[uj];
        float si = 1.f / (1.f + expf(-zi));
        float so = 1.f / (1.f + expf(-zo));
        float cn = si * tanhf(zg);
        cst[sj][uj] = cn;
        P.out[grow + out_off + ucol0 + uj] = so * tanhf(cn);
      }
    }
  }

  for (int t = 1; t < T_; ++t) {
    multi_barrier(&bar[BAR_T(team)], &bar[BAR_T(team) + 16], 32);

    // owner: prefetch this step's G into regs (hidden under main loop)
    float Gp[8][4][2];
    if (owner) {
      #pragma unroll
      for (int sj = 0; sj < 8; ++sj) {
        const size_t grow = (size_t)((s_base + sj) * 64 + t) * ROW_;
        #pragma unroll
        for (int g = 0; g < 4; ++g) {
          float2 v = *(const float2*)&P.out[grow + g * 512 + ucol0];
          Gp[sj][g][0] = v.x; Gp[sj][g][1] = v.y;
        }
      }
    }

    float acc[8][8];
    #pragma unroll
    for (int a = 0; a < 8; ++a)
      #pragma unroll
      for (int b = 0; b < 8; ++b) acc[a][b] = 0.f;

    // h staging: chunk = 64 k of all 32 team samples (2048 f), dbl-buffered
    const int idx0 = tid * 2, idx1 = idx0 + 1;
    const int s0 = idx0 >> 4, kq0 = idx0 & 15;
    const int s1 = idx1 >> 4, kq1 = idx1 & 15;
    const size_t hrow0 = (size_t)((team * 32 + s0) * 64 + (t - 1)) * ROW_ + out_off;
    const size_t hrow1 = (size_t)((team * 32 + s1) * 64 + (t - 1)) * ROW_ + out_off;
    const int c0 = s0 * 64 + ((kq0 * 4 + 8 * (s0 >> 3)) & 63);
    const int c1 = s1 * 64 + ((kq1 * 4 + 8 * (s1 >> 3)) & 63);
    {
      float4 v0 = *(const float4*)&P.out[hrow0 + kq0 * 4];
      float4 v1 = *(const float4*)&P.out[hrow1 + kq1 * 4];
      *(float4*)&smem[HB0_ + c0] = v0;
      *(float4*)&smem[HB0_ + c1] = v1;
    }
    __syncthreads();

    for (int kc = 0; kc < 8; ++kc) {
      float4 nv0 = make_float4(0.f, 0.f, 0.f, 0.f), nv1 = nv0;
      if (kc < 7) {   // issue next-chunk global loads (hidden under FMAs)
        nv0 = *(const float4*)&P.out[hrow0 + (kc + 1) * 64 + kq0 * 4];
        nv1 = *(const float4*)&P.out[hrow1 + (kc + 1) * 64 + kq1 * 4];
      }
      // compute chunk kc: k = kc*64 + kb*8 + kk, kk = 0..7
      const float* wp  = &smem[kc * WKC_ + kb * WKB_ + rg * 8];
      const float* hbv = &smem[HB0_ + (kc & 1) * 2048];
      #pragma unroll
      for (int kq2 = 0; kq2 < 2; ++kq2) {
        float4 h4[8];
        const int colr = kb * 8 + kq2 * 4;
        #pragma unroll
        for (int sj = 0; sj < 8; ++sj)
          h4[sj] = *(const float4*)&hbv[(sgq * 8 + sj) * 64 + ((colr + 8 * sgq) & 63)];
        #pragma unroll
        for (int e = 0; e < 4; ++e) {
          const float4 wA = *(const float4*)&wp[(kq2 * 4 + e) * 64];
          const float4 wB = *(const float4*)&wp[(kq2 * 4 + e) * 64 + 4];
          #pragma unroll
          for (int sj = 0; sj < 8; ++sj) {
            const float hv = (&h4[sj].x)[e];
            acc[sj][0] += hv * wA.x; acc[sj][1] += hv * wA.y;
            acc[sj][2] += hv * wA.z; acc[sj][3] += hv * wA.w;
            acc[sj][4] += hv * wB.x; acc[sj][5] += hv * wB.y;
            acc[sj][6] += hv * wB.z; acc[sj][7] += hv * wB.w;
          }
        }
      }
      if (kc < 7) {
        *(float4*)&smem[HB0_ + ((kc + 1) & 1) * 2048 + c0] = nv0;
        *(float4*)&smem[HB0_ + ((kc + 1) & 1) * 2048 + c1] = nv1;
      }
      __syncthreads();
    }

    // ---- reduce over kb: shfl pair, then 2 LDS slab rounds ----
    #pragma unroll
    for (int a = 0; a < 8; ++a)
      #pragma unroll
      for (int b = 0; b < 8; ++b)
        acc[a][b] += __shfl_xor(acc[a][b], 32, 64);
    const int wv = tid >> 6;
    const bool halfLo = ((tid >> 5) & 1) == 0;
    const int lo = tid & 31;
    float* slab0 = &smem[HB0_];
    float* slab1 = &smem[HB0_ + 2048];
    if (halfLo && wv == 1) WRSLAB(slab0);
    if (halfLo && wv == 3) WRSLAB(slab1);
    __syncthreads();
    if (halfLo && wv == 0) RDSLAB(slab0);
    if (halfLo && wv == 2) RDSLAB(slab1);
    __syncthreads();
    if (halfLo && wv == 2) WRSLAB(slab0);
    __syncthreads();
    if (owner) {
      RDSLAB(slab0);
      // ---- cell update + h write ----
      #pragma unroll
      for (int sj = 0; sj < 8; ++sj) {
        const size_t orow = (size_t)((s_base + sj) * 64 + t) * ROW_;
        #pragma unroll
        for (int uj = 0; uj < 2; ++uj) {
          float zi = Gp[sj][0][uj] + acc[sj][uj * 4 + 0];
          float zf = Gp[sj][1][uj] + acc[sj][uj * 4 + 1];
          float zg = Gp[sj][2][uj] + acc[sj][uj * 4 + 2];
          float zo = Gp[sj][3][uj] + acc[sj][uj * 4 + 3];
          float si = 1.f / (1.f + expf(-zi));
          float sf = 1.f / (1.f + expf(-zf));
          float so = 1.f / (1.f + expf(-zo));
          float cn = sf * cst[sj][uj] + si * tanhf(zg);
          cst[sj][uj] = cn;
          P.out[orow + out_off + ucol0 + uj] = so * tanhf(cn);
        }
      }
    }
  } // t
}

// ---------------- label-routed combine FC (+ length branch, label argmax) ----
__global__ __launch_bounds__(256) void k_combine(Params P) {
  __shared__ float sA[16][CIN_];
  __shared__ float sLen[64];
  int b = blockIdx.x >> 2, t0 = (blockIdx.x & 3) * 16;
  int tid = threadIdx.x;
  int li = P.length[b] - 1;
  if (tid < 64) {
    float v = P.lenW[tid * 64 + li] + P.lenB[tid];
    sLen[tid] = v > 0.f ? v : 0.f;
  }
  float best = P.label[b * 8]; int l = 0;
  #pragma unroll
  for (int k = 1; k < 8; ++k) {
    float lv = P.label[b * 8 + k];
    if (lv > best) { best = lv; l = k; }
  }
  __syncthreads();
  for (int tt = 0; tt < 16; ++tt) {
    int t = t0 + tt;
    for (int k = tid; k < CIN_; k += 256) {
      float v;
      if (k < 640) {
        int a = k >> 7, e = k & 127;
        int xi = P.x[((b * T_ + t) * 5) + a];
        v = P.emb[a][xi * EMB_ + e];
      } else {
        v = sLen[k - 640];
      }
      sA[tt][k] = v;
    }
  }
  __syncthreads();
  int hg = tid & 127, mh = tid >> 7;
  int h = hg * 4, tb = mh * 8;
  const float* W0 = P.combW + ((size_t)(l * HID_ + h)) * CIN_;
  float acc[4][8];
  #pragma unroll
  for (int c = 0; c < 4; ++c)
    #pragma unroll
    for (int m = 0; m < 8; ++m) acc[c][m] = 0.f;
  for (int k = 0; k < CIN_; k += 4) {
    float4 w0 = *(const float4*)(const void*)(W0 + k);
    float4 w1 = *(const float4*)(const void*)(W0 + CIN_ + k);
    float4 w2 = *(const float4*)(const void*)(W0 + 2 * CIN_ + k);
    float4 w3 = *(const float4*)(const void*)(W0 + 3 * CIN_ + k);
    #pragma unroll
    for (int m = 0; m < 8; ++m) {
      float4 av = *(const float4*)&sA[tb + m][k];
      acc[0][m] += w0.x*av.x + w0.y*av.y + w0.z*av.z + w0.w*av.w;
      acc[1][m] += w1.x*av.x + w1.y*av.y + w1.z*av.z + w1.w*av.w;
      acc[2][m] += w2.x*av.x + w2.y*av.y + w2.z*av.z + w2.w*av.w;
      acc[3][m] += w3.x*av.x + w3.y*av.y + w3.z*av.z + w3.w*av.w;
    }
  }
  #pragma unroll
  for (int c = 0; c < 4; ++c) {
    float bias = P.combB[l * HID_ + h + c];
    #pragma unroll
    for (int m = 0; m < 8; ++m) {
      float v = acc[c][m] + bias;
      P.out[((size_t)(b * T_ + t0 + tb + m)) * ROW_ + OFF_HA + h + c] = v > 0.f ? v : 0.f;
    }
  }
}

// ---------------- heads (attr fused) -> logits overwrite own rows ----------
// LDS overlay: sB first holds now_emb (for attr MLPs), then hidden (for the
// main GEMM). 26.6KB total -> 6 blocks/CU.
__global__ __launch_bounds__(256, 6) void k_heads(Params P) {
  __shared__ float sB[8][512];
  __shared__ float sAt[8][5][64];
  int m0 = blockIdx.x * 8;
  int tid = threadIdx.x;
  // stage now_emb
  for (int i = tid; i < 8 * 512; i += 256) {
    int tt = i >> 9, k = i & 511;
    int a = k >> 7, e = k & 127;
    int xi = P.xnow[((m0 + tt) * 5) + a];
    sB[tt][k] = P.emb[a][xi * EMB_ + e];
  }
  for (int i = tid; i < 8 * 64; i += 256) {
    int tt = i >> 6, j = i & 63;
    sAt[tt][0][j] = P.pad[j];
  }
  __syncthreads();
  // attr MLPs (read sB = now_emb)
  {
    int ih = tid >> 6, j = tid & 63;
    int Klen = (ih + 1) * EMB_;
    const float* Wr = P.condW[ih] + (size_t)j * Klen;
    float acc[8] = {0.f,0.f,0.f,0.f,0.f,0.f,0.f,0.f};
    for (int k = 0; k < Klen; k += 4) {
      float4 w = *(const float4*)(const void*)(Wr + k);
      #pragma unroll
      for (int m = 0; m < 8; ++m) {
        float4 av = *(const float4*)&sB[m][k];
        acc[m] += w.x*av.x + w.y*av.y + w.z*av.z + w.w*av.w;
      }
    }
    float bias = P.condB[ih][j];
    #pragma unroll
    for (int m = 0; m < 8; ++m) {
      float v = acc[m] + bias;
      sAt[m][ih + 1][j] = v > 0.f ? v : 0.f;
    }
  }
  __syncthreads();
  // overlay: reload sB with hidden
  for (int i = tid; i < 8 * 512; i += 256) {
    int tt = i >> 9, k = i & 511;
    sB[tt][k] = P.out[((size_t)(m0 + tt)) * ROW_ + OFF_HA + k];
  }
  __syncthreads();
  const int V[5] = {256, 256, 1024, 1024, 512};
  int off = 0;
  int cg = tid & 127, mh = tid >> 7, tb = mh * 4;
  for (int head = 0; head < 5; ++head) {
    const float* W = P.outW[head];
    const float* bias = P.outB[head];
    int Vh = V[head];
    for (int c0 = cg * 4; c0 < Vh; c0 += 512) {
      const float* Wr = W + (size_t)c0 * HA_;
      float acc[4][4];
      #pragma unroll
      for (int c = 0; c < 4; ++c)
        #pragma unroll
        for (int m = 0; m < 4; ++m) acc[c][m] = 0.f;
      for (int k = 0; k < 512; k += 4) {
        float4 w0 = *(const float4*)(const void*)(Wr + k);
        float4 w1 = *(const float4*)(const void*)(Wr + HA_ + k);
        float4 w2 = *(const float4*)(const void*)(Wr + 2 * HA_ + k);
        float4 w3 = *(const float4*)(const void*)(Wr + 3 * HA_ + k);
        #pragma unroll
        for (int m = 0; m < 4; ++m) {
          float4 av = *(const float4*)&sB[tb + m][k];
          acc[0][m] += w0.x*av.x + w0.y*av.y + w0.z*av.z + w0.w*av.w;
          acc[1][m] += w1.x*av.x + w1.y*av.y + w1.z*av.z + w1.w*av.w;
          acc[2][m] += w2.x*av.x + w2.y*av.y + w2.z*av.z + w2.w*av.w;
          acc[3][m] += w3.x*av.x + w3.y*av.y + w3.z*av.z + w3.w*av.w;
        }
      }
      for (int k = 0; k < 64; k += 4) {
        float4 w0 = *(const float4*)(const void*)(Wr + 512 + k);
        float4 w1 = *(const float4*)(const void*)(Wr + HA_ + 512 + k);
        float4 w2 = *(const float4*)(const void*)(Wr + 2 * HA_ + 512 + k);
        float4 w3 = *(const float4*)(const void*)(Wr + 3 * HA_ + 512 + k);
        #pragma unroll
        for (int m = 0; m < 4; ++m) {
          float4 av = *(const float4*)&sAt[tb + m][head][k];
          acc[0][m] += w0.x*av.x + w0.y*av.y + w0.z*av.z + w0.w*av.w;
          acc[1][m] += w1.x*av.x + w1.y*av.y + w1.z*av.z + w1.w*av.w;
          acc[2][m] += w2.x*av.x + w2.y*av.y + w2.z*av.z + w2.w*av.w;
          acc[3][m] += w3.x*av.x + w3.y*av.y + w3.z*av.z + w3.w*av.w;
        }
      }
      #pragma unroll
      for (int c = 0; c < 4; ++c) {
        float bi = bias[c0 + c];
        #pragma unroll
        for (int m = 0; m < 4; ++m)
          P.out[((size_t)(m0 + tb + m)) * ROW_ + off + c0 + c] = acc[c][m] + bi;
      }
    }
    off += Vh;
  }
}

// ---------------- in-place log_softmax over each head's slice ----------------
__global__ __launch_bounds__(256) void k_lsm(Params P) {
  __shared__ float sred[4];
  int m = blockIdx.x;
  float* row0 = P.out + (size_t)m * ROW_;
  int tid = threadIdx.x, lane = tid & 63, wid = tid >> 6;
  const int V[5] = {256, 256, 1024, 1024, 512};
  int off = 0;
  for (int head = 0; head < 5; ++head) {
    float* row = row0 + off; int Vh = V[head];
    float mx = -1e30f;
    for (int c = tid; c < Vh; c += 256) mx = fmaxf(mx, row[c]);
    for (int o = 32; o > 0; o >>= 1) mx = fmaxf(mx, __shfl_down(mx, o, 64));
    if (lane == 0) sred[wid] = mx;
    __syncthreads();
    mx = fmaxf(fmaxf(sred[0], sred[1]), fmaxf(sred[2], sred[3]));
    __syncthreads();
    float s = 0.f;
    for (int c = tid; c < Vh; c += 256) s += expf(row[c] - mx);
    for (int o = 32; o > 0; o >>= 1) s += __shfl_down(s, o, 64);
    if (lane == 0) sred[wid] = s;
    __syncthreads();
    float lse = mx + logf(sred[0] + sred[1] + sred[2] + sred[3]);
    __syncthreads();
    for (int c = tid; c < Vh; c += 256) row[c] = row[c] - lse;
    off += Vh;
  }
}

extern "C" void kernel_launch(void* const* d_in, const int* in_sizes, int n_in,
                              void* d_out, int out_size, void* d_ws, size_t ws_size,
                              hipStream_t stream) {
  (void)in_sizes; (void)n_in; (void)out_size; (void)ws_size;
  Params P;
  P.label  = (const float*)d_in[0];
  P.length = (const int*)  d_in[1];
  P.x      = (const int*)  d_in[2];
  P.xnow   = (const int*)  d_in[3];
  for (int i = 0; i < 5; ++i) P.emb[i] = (const float*)d_in[4 + i];
  P.pad = (const float*)d_in[9];
  for (int i = 0; i < 4; ++i) {
    P.condW[i] = (const float*)d_in[10 + 2 * i];
    P.condB[i] = (const float*)d_in[11 + 2 * i];
  }
  P.lenW  = (const float*)d_in[18]; P.lenB  = (const float*)d_in[19];
  P.combW = (const float*)d_in[20]; P.combB = (const float*)d_in[21];
  P.Wih   = (const float*)d_in[22]; P.Whh   = (const float*)d_in[23];
  P.bih   = (const float*)d_in[24]; P.bhh   = (const float*)d_in[25];
  for (int i = 0; i < 5; ++i) {
    P.outW[i] = (const float*)d_in[26 + 2 * i];
    P.outB[i] = (const float*)d_in[27 + 2 * i];
  }
  P.bar = (unsigned int*)d_ws;
  P.out = (float*)d_out;

  hipMemsetAsync(d_ws, 0, 1536, stream);
  k_combine<<<1024, 256, 0, stream>>>(P);
  for (int l = 0; l < 4; ++l) {
    k_t1 <<<256,  256, 0, stream>>>(P, l);
    k_gih<<<1024, 256, 0, stream>>>(P, l);
    void* args[] = { &P, &l };
    hipLaunchCooperativeKernel((void*)k_lstmB, dim3(256), dim3(256), args, 0, stream);
  }
  k_heads<<<2048,  256, 0, stream>>>(P);
  k_lsm  <<<16384, 256, 0, stream>>>(P);
}

// Round 6
// 11850.941 us; speedup vs baseline: 1.2049x; 1.2049x over previous
//
#include <hip/hip_runtime.h>
#include <math.h>

// ---------------------------------------------------------------------------
// Generator_429496729630 — round 8: k_heads -> per-head weight-resident GEMM.
//
// r7 post-mortem: LDS overlay doubled occupancy (29->51%) but dur went 3.9->
// 4.35ms => k_heads is NOT latency-bound; it's throughput-bound on weight
// delivery: 2048 blocks x 7.08MB weight stream = 14.5GB through L2/L3 at an
// observed ~3.7TB/s, and 7MB > 4MB per-XCD L2 so much of it misses to L3.
// More waves made the thrash worse.
//
// Fix: (1) M-tile 8->32 rows/block (4x less weight traffic: 3.6GB);
// (2) one kernel PER HEAD: the ~512 resident blocks then share ONE head's
// weight panel (0.59-2.36MB) which fits per-XCD L2 -> weights served at L2
// BW, kernel becomes VALU-bound (floor 370us @ 157TF).
// (3) ordering: head 3's logits (cols 1536-2559) overwrite live hidden
// (OFF_HA 2048-2559) -> launch heads 0,1,2,4 first, head 3 LAST.
// Per-output FP accumulation order identical everywhere (absmax unchanged).
// All other kernels untouched from r7.
// ---------------------------------------------------------------------------

#define B_    256
#define T_    64
#define EMB_  128
#define HID_  512
#define G4_   2048
#define CIN_  704
#define HA_   576
#define ROW_  3072
#define OFF_HA 2048
#define OFF_HB 2560

// phase-B LDS geometry (float indices)
#define WKB_   516            // kb-subblock stride: 8*64 + 4 pad (bank spread)
#define WKC_   4128           // kc-block stride: 8*WKB_
#define HB0_   33024          // = 8*WKC_ ; hbuf / reduction-slab region (2 x 2048)
#define SMEM_F 37120          // 145 KiB

// barrier word layout in ws: team tau: cnt @ 64 + tau*32, gen @ +16
#define BAR_T(tau) (64 + (tau) * 32)

struct Params {
  const float* label; const int* length; const int* x; const int* xnow;
  const float* emb[5]; const float* pad;
  const float* condW[4]; const float* condB[4];
  const float* lenW; const float* lenB;
  const float* combW; const float* combB;
  const float* Wih; const float* Whh; const float* bih; const float* bhh;
  const float* outW[5]; const float* outB[5];
  unsigned int* bar;
  float* out;
};

// generation-based multi-block barrier (agent scope).
__device__ __forceinline__ void multi_barrier(unsigned int* cnt, unsigned int* gen,
                                              unsigned int n) {
  __syncthreads();
  if (threadIdx.x == 0) {
    unsigned int g = __hip_atomic_load(gen, __ATOMIC_RELAXED, __HIP_MEMORY_SCOPE_AGENT);
    unsigned int a = __hip_atomic_fetch_add(cnt, 1u, __ATOMIC_ACQ_REL, __HIP_MEMORY_SCOPE_AGENT);
    if (a == n - 1u) {
      __hip_atomic_store(cnt, 0u, __ATOMIC_RELAXED, __HIP_MEMORY_SCOPE_AGENT);
      __hip_atomic_store(gen, g + 1u, __ATOMIC_RELEASE, __HIP_MEMORY_SCOPE_AGENT);
    } else {
      while (__hip_atomic_load(gen, __ATOMIC_RELAXED, __HIP_MEMORY_SCOPE_AGENT) == g) {
        __builtin_amdgcn_s_sleep(2);
      }
      (void)__hip_atomic_load(gen, __ATOMIC_ACQUIRE, __HIP_MEMORY_SCOPE_AGENT);
    }
  }
  __syncthreads();
}

// reduction-slab helpers: lane lo writes/reads its acc[8][8] as 16 float4,
// column-rotated by lane for bank spread.
#define WRSLAB(SL) do { \
  _Pragma("unroll") \
  for (int qq = 0; qq < 16; ++qq) { \
    int cc = ((qq + lo) & 15) * 4; \
    *(float4*)&(SL)[lo * 64 + cc] = \
      make_float4(acc[qq >> 1][(qq & 1) * 4 + 0], acc[qq >> 1][(qq & 1) * 4 + 1], \
                  acc[qq >> 1][(qq & 1) * 4 + 2], acc[qq >> 1][(qq & 1) * 4 + 3]); \
  } } while (0)

#define RDSLAB(SL) do { \
  _Pragma("unroll") \
  for (int qq = 0; qq < 16; ++qq) { \
    int cc = ((qq + lo) & 15) * 4; \
    float4 vv = *(const float4*)&(SL)[lo * 64 + cc]; \
    acc[qq >> 1][(qq & 1) * 4 + 0] += vv.x; acc[qq >> 1][(qq & 1) * 4 + 1] += vv.y; \
    acc[qq >> 1][(qq & 1) * 4 + 2] += vv.z; acc[qq >> 1][(qq & 1) * 4 + 3] += vv.w; \
  } } while (0)

// ---------------- T1: transpose Wih -> Wt_ih into OUT slot ----------------
__global__ __launch_bounds__(256) void k_t1(Params P, int l) {
  __shared__ float sm[4608];
  const int out_off = (l & 1) ? OFF_HA : OFF_HB;
  const float* Wih = P.Wih + (size_t)l * G4_ * HID_;
  const int tid = threadIdx.x, blk = blockIdx.x;
  const int rt = blk >> 4, kt = blk & 15;
  const int r0 = rt * 128, k0 = kt * 32;
  const int ul = tid >> 3, kl = (tid & 7) * 4;
  #pragma unroll
  for (int p = 0; p < 4; ++p) {
    float4 v = *(const float4*)(Wih + (size_t)(r0 + p * 32 + ul) * HID_ + k0 + kl);
    *(float4*)&sm[(p * 32 + ul) * 36 + kl] = v;
  }
  __syncthreads();
  const int kk = tid >> 3, qb = (tid & 7) * 4;
  #pragma unroll
  for (int p = 0; p < 4; ++p) {
    int rl = qb + p * 32;
    float4 v = make_float4(sm[(rl + 0) * 36 + kk], sm[(rl + 1) * 36 + kk],
                           sm[(rl + 2) * 36 + kk], sm[(rl + 3) * 36 + kk]);
    int kabs = k0 + kk;
    int row = (r0 >> 8) * 256 + (kabs >> 1);
    int col = out_off + (kabs & 1) * 256 + (r0 & 255) + rl;
    *(float4*)&P.out[(size_t)row * ROW_ + col] = v;
  }
}

// ---------------- A: G = h_in @ Wih^T + bih + bhh ----------------
__global__ __launch_bounds__(256, 3) void k_gih(Params P, int l) {
  const int in_off  = (l & 1) ? OFF_HB : OFF_HA;
  const int out_off = (l & 1) ? OFF_HA : OFF_HB;
  const int tid = threadIdx.x;
  const int rg = tid & 63, mh = tid >> 6;
  const int rb = blockIdx.x >> 1, ch = blockIdx.x & 1;
  const int m_base = rb * 32;
  const float* arow[8];
  #pragma unroll
  for (int mm = 0; mm < 8; ++mm)
    arow[mm] = P.out + (size_t)(m_base + mh * 8 + mm) * ROW_ + in_off;
  for (int p0 = 0; p0 < 4; ++p0) {
    const int p = ch * 4 + p0;
    float acc[4][8];
    #pragma unroll
    for (int c = 0; c < 4; ++c)
      #pragma unroll
      for (int m = 0; m < 8; ++m) acc[c][m] = 0.f;
    const float* wp = P.out + (size_t)(p * 256) * ROW_ + out_off + rg * 4;
    for (int kq = 0; kq < 64; ++kq) {
      float4 w0 = *(const float4*)(wp);              // k=4kq
      float4 w1 = *(const float4*)(wp + 256);        // k=4kq+1
      float4 w2 = *(const float4*)(wp + ROW_);       // k=4kq+2
      float4 w3 = *(const float4*)(wp + ROW_ + 256); // k=4kq+3
      #pragma unroll
      for (int mm = 0; mm < 8; ++mm) {
        float4 a = *(const float4*)(arow[mm] + kq * 4);
        acc[0][mm] += w0.x * a.x + w1.x * a.y + w2.x * a.z + w3.x * a.w;
        acc[1][mm] += w0.y * a.x + w1.y * a.y + w2.y * a.z + w3.y * a.w;
        acc[2][mm] += w0.z * a.x + w1.z * a.y + w2.z * a.z + w3.z * a.w;
        acc[3][mm] += w0.w * a.x + w1.w * a.y + w2.w * a.z + w3.w * a.w;
      }
      wp += 2 * ROW_;
    }
    int r4 = p * 256 + rg * 4;
    float4 bi = *(const float4*)(P.bih + l * G4_ + r4);
    float4 bh = *(const float4*)(P.bhh + l * G4_ + r4);
    float bx = bi.x + bh.x, by = bi.y + bh.y, bz = bi.z + bh.z, bw = bi.w + bh.w;
    #pragma unroll
    for (int mm = 0; mm < 8; ++mm) {
      int m = m_base + mh * 8 + mm;
      *(float4*)&P.out[(size_t)m * ROW_ + r4] =
        make_float4(acc[0][mm] + bx, acc[1][mm] + by,
                    acc[2][mm] + bz, acc[3][mm] + bw);
    }
  }
}

// ---------------- B: recurrent steps, Whh slice resident in LDS ----------
__global__ __launch_bounds__(256, 1) void k_lstmB(Params P, int l) {
  __shared__ float smem[SMEM_F];
  unsigned int* bar = P.bar;
  const int tid = threadIdx.x;
  const int blk = blockIdx.x;
  const int team = blk & 7, member = blk >> 3;   // 8 teams x 32 members
  const int out_off = (l & 1) ? OFF_HA : OFF_HB;

  const int kb  = tid >> 5;          // 0..7 k-slice
  const int sgq = (tid >> 3) & 3;    // 0..3 sample group (8 samples)
  const int rg  = tid & 7;           // 0..7 row group
  const bool owner = (tid < 32);
  const int s_base = team * 32 + sgq * 8;
  const int ucol0  = member * 16 + rg * 2;

  // load this member's Whh slice: local row r = i*4+g  (i=unit&15, g=gate)
  {
    const float* Wl = P.Whh + (size_t)l * G4_ * HID_;
    const int r = tid >> 2, q = tid & 3;
    const float* src = Wl + (size_t)((r & 3) * 512 + member * 16 + (r >> 2)) * HID_
                       + q * 128;
    for (int j = 0; j < 32; ++j) {
      float4 v = *(const float4*)(src + j * 4);
      int k0 = q * 128 + j * 4;
      #pragma unroll
      for (int e = 0; e < 4; ++e) {
        int k = k0 + e;
        smem[(k >> 6) * WKC_ + ((k >> 3) & 7) * WKB_ + (k & 7) * 64 + r] = (&v.x)[e];
      }
    }
  }
  __syncthreads();

  float cst[8][2];   // owner c-state: 8 samples x 2 units

  // ---- t = 0: h_prev = 0, gates = G directly ----
  if (owner) {
    #pragma unroll
    for (int sj = 0; sj < 8; ++sj) {
      const size_t grow = (size_t)((s_base + sj) * 64 + 0) * ROW_;
      float2 zi2 = *(const float2*)&P.out[grow + 0 * 512 + ucol0];
      float2 zg2 = *(const float2*)&P.out[grow + 2 * 512 + ucol0];
      float2 zo2 = *(const float2*)&P.out[grow + 3 * 512 + ucol0];
      #pragma unroll
      for (int uj = 0; uj < 2; ++uj) {
        float zi = (&zi2.x)[uj], zg = (&zg2.x)[uj], zo = (&zo2.x)[uj];
        float si = 1.f / (1.f + expf(-zi));
        float so = 1.f / (1.f + expf(-zo));
        float cn = si * tanhf(zg);
        cst[sj][uj] = cn;
        P.out[grow + out_off + ucol0 + uj] = so * tanhf(cn);
      }
    }
  }

  for (int t = 1; t < T_; ++t) {
    multi_barrier(&bar[BAR_T(team)], &bar[BAR_T(team) + 16], 32);

    // owner: prefetch this step's G into regs (hidden under main loop)
    float Gp[8][4][2];
    if (owner) {
      #pragma unroll
      for (int sj = 0; sj < 8; ++sj) {
        const size_t grow = (size_t)((s_base + sj) * 64 + t) * ROW_;
        #pragma unroll
        for (int g = 0; g < 4; ++g) {
          float2 v = *(const float2*)&P.out[grow + g * 512 + ucol0];
          Gp[sj][g][0] = v.x; Gp[sj][g][1] = v.y;
        }
      }
    }

    float acc[8][8];
    #pragma unroll
    for (int a = 0; a < 8; ++a)
      #pragma unroll
      for (int b = 0; b < 8; ++b) acc[a][b] = 0.f;

    // h staging: chunk = 64 k of all 32 team samples (2048 f), dbl-buffered
    const int idx0 = tid * 2, idx1 = idx0 + 1;
    const int s0 = idx0 >> 4, kq0 = idx0 & 15;
    const int s1 = idx1 >> 4, kq1 = idx1 & 15;
    const size_t hrow0 = (size_t)((team * 32 + s0) * 64 + (t - 1)) * ROW_ + out_off;
    const size_t hrow1 = (size_t)((team * 32 + s1) * 64 + (t - 1)) * ROW_ + out_off;
    const int c0 = s0 * 64 + ((kq0 * 4 + 8 * (s0 >> 3)) & 63);
    const int c1 = s1 * 64 + ((kq1 * 4 + 8 * (s1 >> 3)) & 63);
    {
      float4 v0 = *(const float4*)&P.out[hrow0 + kq0 * 4];
      float4 v1 = *(const float4*)&P.out[hrow1 + kq1 * 4];
      *(float4*)&smem[HB0_ + c0] = v0;
      *(float4*)&smem[HB0_ + c1] = v1;
    }
    __syncthreads();

    for (int kc = 0; kc < 8; ++kc) {
      float4 nv0 = make_float4(0.f, 0.f, 0.f, 0.f), nv1 = nv0;
      if (kc < 7) {   // issue next-chunk global loads (hidden under FMAs)
        nv0 = *(const float4*)&P.out[hrow0 + (kc + 1) * 64 + kq0 * 4];
        nv1 = *(const float4*)&P.out[hrow1 + (kc + 1) * 64 + kq1 * 4];
      }
      // compute chunk kc: k = kc*64 + kb*8 + kk, kk = 0..7
      const float* wp  = &smem[kc * WKC_ + kb * WKB_ + rg * 8];
      const float* hbv = &smem[HB0_ + (kc & 1) * 2048];
      #pragma unroll
      for (int kq2 = 0; kq2 < 2; ++kq2) {
        float4 h4[8];
        const int colr = kb * 8 + kq2 * 4;
        #pragma unroll
        for (int sj = 0; sj < 8; ++sj)
          h4[sj] = *(const float4*)&hbv[(sgq * 8 + sj) * 64 + ((colr + 8 * sgq) & 63)];
        #pragma unroll
        for (int e = 0; e < 4; ++e) {
          const float4 wA = *(const float4*)&wp[(kq2 * 4 + e) * 64];
          const float4 wB = *(const float4*)&wp[(kq2 * 4 + e) * 64 + 4];
          #pragma unroll
          for (int sj = 0; sj < 8; ++sj) {
            const float hv = (&h4[sj].x)[e];
            acc[sj][0] += hv * wA.x; acc[sj][1] += hv * wA.y;
            acc[sj][2] += hv * wA.z; acc[sj][3] += hv * wA.w;
            acc[sj][4] += hv * wB.x; acc[sj][5] += hv * wB.y;
            acc[sj][6] += hv * wB.z; acc[sj][7] += hv * wB.w;
          }
        }
      }
      if (kc < 7) {
        *(float4*)&smem[HB0_ + ((kc + 1) & 1) * 2048 + c0] = nv0;
        *(float4*)&smem[HB0_ + ((kc + 1) & 1) * 2048 + c1] = nv1;
      }
      __syncthreads();
    }

    // ---- reduce over kb: shfl pair, then 2 LDS slab rounds ----
    #pragma unroll
    for (int a = 0; a < 8; ++a)
      #pragma unroll
      for (int b = 0; b < 8; ++b)
        acc[a][b] += __shfl_xor(acc[a][b], 32, 64);
    const int wv = tid >> 6;
    const bool halfLo = ((tid >> 5) & 1) == 0;
    const int lo = tid & 31;
    float* slab0 = &smem[HB0_];
    float* slab1 = &smem[HB0_ + 2048];
    if (halfLo && wv == 1) WRSLAB(slab0);
    if (halfLo && wv == 3) WRSLAB(slab1);
    __syncthreads();
    if (halfLo && wv == 0) RDSLAB(slab0);
    if (halfLo && wv == 2) RDSLAB(slab1);
    __syncthreads();
    if (halfLo && wv == 2) WRSLAB(slab0);
    __syncthreads();
    if (owner) {
      RDSLAB(slab0);
      // ---- cell update + h write ----
      #pragma unroll
      for (int sj = 0; sj < 8; ++sj) {
        const size_t orow = (size_t)((s_base + sj) * 64 + t) * ROW_;
        #pragma unroll
        for (int uj = 0; uj < 2; ++uj) {
          float zi = Gp[sj][0][uj] + acc[sj][uj * 4 + 0];
          float zf = Gp[sj][1][uj] + acc[sj][uj * 4 + 1];
          float zg = Gp[sj][2][uj] + acc[sj][uj * 4 + 2];
          float zo = Gp[sj][3][uj] + acc[sj][uj * 4 + 3];
          float si = 1.f / (1.f + expf(-zi));
          float sf = 1.f / (1.f + expf(-zf));
          float so = 1.f / (1.f + expf(-zo));
          float cn = sf * cst[sj][uj] + si * tanhf(zg);
          cst[sj][uj] = cn;
          P.out[orow + out_off + ucol0 + uj] = so * tanhf(cn);
        }
      }
    }
  } // t
}

// ---------------- label-routed combine FC (+ length branch, label argmax) ----
__global__ __launch_bounds__(256) void k_combine(Params P) {
  __shared__ float sA[16][CIN_];
  __shared__ float sLen[64];
  int b = blockIdx.x >> 2, t0 = (blockIdx.x & 3) * 16;
  int tid = threadIdx.x;
  int li = P.length[b] - 1;
  if (tid < 64) {
    float v = P.lenW[tid * 64 + li] + P.lenB[tid];
    sLen[tid] = v > 0.f ? v : 0.f;
  }
  float best = P.label[b * 8]; int l = 0;
  #pragma unroll
  for (int k = 1; k < 8; ++k) {
    float lv = P.label[b * 8 + k];
    if (lv > best) { best = lv; l = k; }
  }
  __syncthreads();
  for (int tt = 0; tt < 16; ++tt) {
    int t = t0 + tt;
    for (int k = tid; k < CIN_; k += 256) {
      float v;
      if (k < 640) {
        int a = k >> 7, e = k & 127;
        int xi = P.x[((b * T_ + t) * 5) + a];
        v = P.emb[a][xi * EMB_ + e];
      } else {
        v = sLen[k - 640];
      }
      sA[tt][k] = v;
    }
  }
  __syncthreads();
  int hg = tid & 127, mh = tid >> 7;
  int h = hg * 4, tb = mh * 8;
  const float* W0 = P.combW + ((size_t)(l * HID_ + h)) * CIN_;
  float acc[4][8];
  #pragma unroll
  for (int c = 0; c < 4; ++c)
    #pragma unroll
    for (int m = 0; m < 8; ++m) acc[c][m] = 0.f;
  for (int k = 0; k < CIN_; k += 4) {
    float4 w0 = *(const float4*)(const void*)(W0 + k);
    float4 w1 = *(const float4*)(const void*)(W0 + CIN_ + k);
    float4 w2 = *(const float4*)(const void*)(W0 + 2 * CIN_ + k);
    float4 w3 = *(const float4*)(const void*)(W0 + 3 * CIN_ + k);
    #pragma unroll
    for (int m = 0; m < 8; ++m) {
      float4 av = *(const float4*)&sA[tb + m][k];
      acc[0][m] += w0.x*av.x + w0.y*av.y + w0.z*av.z + w0.w*av.w;
      acc[1][m] += w1.x*av.x + w1.y*av.y + w1.z*av.z + w1.w*av.w;
      acc[2][m] += w2.x*av.x + w2.y*av.y + w2.z*av.z + w2.w*av.w;
      acc[3][m] += w3.x*av.x + w3.y*av.y + w3.z*av.z + w3.w*av.w;
    }
  }
  #pragma unroll
  for (int c = 0; c < 4; ++c) {
    float bias = P.combB[l * HID_ + h + c];
    #pragma unroll
    for (int m = 0; m < 8; ++m) {
      float v = acc[c][m] + bias;
      P.out[((size_t)(b * T_ + t0 + tb + m)) * ROW_ + OFF_HA + h + c] = v > 0.f ? v : 0.f;
    }
  }
}

// ---------------- per-head GEMM: 32 rows/block, one head per launch --------
// LDS: sB[32][512] (now_emb overlay -> hidden) 64KB + sAt[32][64] 8KB = 72KB
// -> 2 blocks/CU. Resident cohort (~512 blocks) all stream this head's weight
// panel (0.59-2.36MB) -> fits per-XCD L2.
template<int HEAD, int VH, int OFF>
__global__ __launch_bounds__(256, 2) void k_head(Params P) {
  __shared__ float sB[32][512];
  __shared__ float sAt[32][64];
  const int tid = threadIdx.x;
  const int m0 = blockIdx.x * 32;
  if (HEAD == 0) {
    for (int i = tid; i < 32 * 64; i += 256) sAt[i >> 6][i & 63] = P.pad[i & 63];
  } else {
    const int KA = HEAD * EMB_;
    // stage now_emb[:, :KA]
    for (int i = tid; i < 32 * KA; i += 256) {
      int tt = i / KA, k = i - tt * KA;
      int a = k >> 7, e = k & 127;
      int xi = P.xnow[((m0 + tt) * 5) + a];
      sB[tt][k] = P.emb[a][xi * EMB_ + e];
    }
    __syncthreads();
    // attr MLP: thread (rg=tid>>6, j=tid&63) -> rows rg*8..+7, col j
    int rg = tid >> 6, j = tid & 63;
    const float* Wr = P.condW[HEAD - 1] + (size_t)j * KA;
    float acc[8] = {0.f,0.f,0.f,0.f,0.f,0.f,0.f,0.f};
    for (int k = 0; k < KA; k += 4) {
      float4 w = *(const float4*)(const void*)(Wr + k);
      #pragma unroll
      for (int m = 0; m < 8; ++m) {
        float4 av = *(const float4*)&sB[rg * 8 + m][k];
        acc[m] += w.x*av.x + w.y*av.y + w.z*av.z + w.w*av.w;
      }
    }
    float bias = P.condB[HEAD - 1][j];
    #pragma unroll
    for (int m = 0; m < 8; ++m) {
      float v = acc[m] + bias;
      sAt[rg * 8 + m][j] = v > 0.f ? v : 0.f;
    }
    __syncthreads();
  }
  // overlay: load hidden into sB
  for (int i = tid; i < 32 * 512; i += 256) {
    int tt = i >> 9, k = i & 511;
    sB[tt][k] = P.out[((size_t)(m0 + tt)) * ROW_ + OFF_HA + k];
  }
  __syncthreads();
  // main GEMM: CG col-groups x RPG rows/thread
  constexpr int CG  = (VH >= 512) ? 128 : 64;
  constexpr int RPG = (VH >= 512) ? 16 : 8;
  const int cg = tid & (CG - 1), mh = tid / CG;
  const int tb = mh * RPG;
  const float* Wb = P.outW[HEAD];
  const float* bs = P.outB[HEAD];
  for (int c0 = cg * 4; c0 < VH; c0 += CG * 4) {
    const float* Wr = Wb + (size_t)c0 * HA_;
    float acc2[4][RPG];
    #pragma unroll
    for (int c = 0; c < 4; ++c)
      #pragma unroll
      for (int m = 0; m < RPG; ++m) acc2[c][m] = 0.f;
    for (int k = 0; k < 512; k += 4) {
      float4 w0 = *(const float4*)(const void*)(Wr + k);
      float4 w1 = *(const float4*)(const void*)(Wr + HA_ + k);
      float4 w2 = *(const float4*)(const void*)(Wr + 2 * HA_ + k);
      float4 w3 = *(const float4*)(const void*)(Wr + 3 * HA_ + k);
      #pragma unroll
      for (int m = 0; m < RPG; ++m) {
        float4 av = *(const float4*)&sB[tb + m][k];
        acc2[0][m] += w0.x*av.x + w0.y*av.y + w0.z*av.z + w0.w*av.w;
        acc2[1][m] += w1.x*av.x + w1.y*av.y + w1.z*av.z + w1.w*av.w;
        acc2[2][m] += w2.x*av.x + w2.y*av.y + w2.z*av.z + w2.w*av.w;
        acc2[3][m] += w3.x*av.x + w3.y*av.y + w3.z*av.z + w3.w*av.w;
      }
    }
    for (int k = 0; k < 64; k += 4) {
      float4 w0 = *(const float4*)(const void*)(Wr + 512 + k);
      float4 w1 = *(const float4*)(const void*)(Wr + HA_ + 512 + k);
      float4 w2 = *(const float4*)(const void*)(Wr + 2 * HA_ + 512 + k);
      float4 w3 = *(const float4*)(const void*)(Wr + 3 * HA_ + 512 + k);
      #pragma unroll
      for (int m = 0; m < RPG; ++m) {
        float4 av = *(const float4*)&sAt[tb + m][k];
        acc2[0][m] += w0.x*av.x + w0.y*av.y + w0.z*av.z + w0.w*av.w;
        acc2[1][m] += w1.x*av.x + w1.y*av.y + w1.z*av.z + w1.w*av.w;
        acc2[2][m] += w2.x*av.x + w2.y*av.y + w2.z*av.z + w2.w*av.w;
        acc2[3][m] += w3.x*av.x + w3.y*av.y + w3.z*av.z + w3.w*av.w;
      }
    }
    #pragma unroll
    for (int c = 0; c < 4; ++c) {
      float bi = bs[c0 + c];
      #pragma unroll
      for (int m = 0; m < RPG; ++m)
        P.out[((size_t)(m0 + tb + m)) * ROW_ + OFF + c0 + c] = acc2[c][m] + bi;
    }
  }
}

// ---------------- in-place log_softmax over each head's slice ----------------
__global__ __launch_bounds__(256) void k_lsm(Params P) {
  __shared__ float sred[4];
  int m = blockIdx.x;
  float* row0 = P.out + (size_t)m * ROW_;
  int tid = threadIdx.x, lane = tid & 63, wid = tid >> 6;
  const int V[5] = {256, 256, 1024, 1024, 512};
  int off = 0;
  for (int head = 0; head < 5; ++head) {
    float* row = row0 + off; int Vh = V[head];
    float mx = -1e30f;
    for (int c = tid; c < Vh; c += 256) mx = fmaxf(mx, row[c]);
    for (int o = 32; o > 0; o >>= 1) mx = fmaxf(mx, __shfl_down(mx, o, 64));
    if (lane == 0) sred[wid] = mx;
    __syncthreads();
    mx = fmaxf(fmaxf(sred[0], sred[1]), fmaxf(sred[2], sred[3]));
    __syncthreads();
    float s = 0.f;
    for (int c = tid; c < Vh; c += 256) s += expf(row[c] - mx);
    for (int o = 32; o > 0; o >>= 1) s += __shfl_down(s, o, 64);
    if (lane == 0) sred[wid] = s;
    __syncthreads();
    float lse = mx + logf(sred[0] + sred[1] + sred[2] + sred[3]);
    __syncthreads();
    for (int c = tid; c < Vh; c += 256) row[c] = row[c] - lse;
    off += Vh;
  }
}

extern "C" void kernel_launch(void* const* d_in, const int* in_sizes, int n_in,
                              void* d_out, int out_size, void* d_ws, size_t ws_size,
                              hipStream_t stream) {
  (void)in_sizes; (void)n_in; (void)out_size; (void)ws_size;
  Params P;
  P.label  = (const float*)d_in[0];
  P.length = (const int*)  d_in[1];
  P.x      = (const int*)  d_in[2];
  P.xnow   = (const int*)  d_in[3];
  for (int i = 0; i < 5; ++i) P.emb[i] = (const float*)d_in[4 + i];
  P.pad = (const float*)d_in[9];
  for (int i = 0; i < 4; ++i) {
    P.condW[i] = (const float*)d_in[10 + 2 * i];
    P.condB[i] = (const float*)d_in[11 + 2 * i];
  }
  P.lenW  = (const float*)d_in[18]; P.lenB  = (const float*)d_in[19];
  P.combW = (const float*)d_in[20]; P.combB = (const float*)d_in[21];
  P.Wih   = (const float*)d_in[22]; P.Whh   = (const float*)d_in[23];
  P.bih   = (const float*)d_in[24]; P.bhh   = (const float*)d_in[25];
  for (int i = 0; i < 5; ++i) {
    P.outW[i] = (const float*)d_in[26 + 2 * i];
    P.outB[i] = (const float*)d_in[27 + 2 * i];
  }
  P.bar = (unsigned int*)d_ws;
  P.out = (float*)d_out;

  hipMemsetAsync(d_ws, 0, 1536, stream);
  k_combine<<<1024, 256, 0, stream>>>(P);
  for (int l = 0; l < 4; ++l) {
    k_t1 <<<256,  256, 0, stream>>>(P, l);
    k_gih<<<1024, 256, 0, stream>>>(P, l);
    void* args[] = { &P, &l };
    hipLaunchCooperativeKernel((void*)k_lstmB, dim3(256), dim3(256), args, 0, stream);
  }
  // heads: 0,1,2,4 first; head 3 LAST (its logits cols 1536-2559 overwrite the
  // live hidden slot OFF_HA 2048-2559 that the other heads' blocks read).
  k_head<0,  256,    0><<<512, 256, 0, stream>>>(P);
  k_head<1,  256,  256><<<512, 256, 0, stream>>>(P);
  k_head<2, 1024,  512><<<512, 256, 0, stream>>>(P);
  k_head<4,  512, 2560><<<512, 256, 0, stream>>>(P);
  k_head<3, 1024, 1536><<<512, 256, 0, stream>>>(P);
  k_lsm<<<16384, 256, 0, stream>>>(P);
}